// Round 3
// baseline (99.640 us; speedup 1.0000x reference)
//
#include <hip/hip_runtime.h>
#include <math.h>

#define C_IN  32
#define O_OUT 32
#define HIMG  112
#define WIMG  112
#define TS    8     // spatial tile 8x8
#define OG    8     // output channels per wave (4 waves x 8 = 32)
#define LROW  12    // padded row stride: (12*(ty+kh)+tx+kw)%32 -> exactly 2 lanes/bank (free)
#define LPLANE (10 * LROW)   // 120 floats per channel plane

// Tropical (max-min) 3x3 conv, 'same' padding with -inf.
// out[n,o,i,j] = max_{c,kh,kw} min(x[n,c,i+kh-1,j+kw-1], w[o,c,kh,kw])
__global__ __launch_bounds__(256, 6) void semiconv_kernel(
    const float* __restrict__ x, const float* __restrict__ kern,
    float* __restrict__ out)
{
    __shared__ float lds[C_IN * LPLANE];   // 15360 B

    const int tid = threadIdx.x;
    const int tj0 = blockIdx.x * TS;
    const int ti0 = blockIdx.y * TS;
    const int n   = blockIdx.z;

    const float* xn = x + (size_t)n * (C_IN * HIMG * WIMG);

    // Stage x[n, :, ti0-1 .. ti0+8, tj0-1 .. tj0+8] into padded rows (cols 10,11
    // are never read). Exactly 15 iterations of 256.
    #pragma unroll 1
    for (int idx = tid; idx < C_IN * LPLANE; idx += 256) {
        int c   = idx / LPLANE;
        int rem = idx - c * LPLANE;
        int r   = rem / LROW;
        int col = rem - r * LROW;
        int gi = ti0 - 1 + r;
        int gj = tj0 - 1 + col;
        float v = -INFINITY;
        if (col < 10 && (unsigned)gi < (unsigned)HIMG && (unsigned)gj < (unsigned)WIMG)
            v = xn[c * (HIMG * WIMG) + gi * WIMG + gj];
        lds[idx] = v;
    }
    __syncthreads();

    const int sp = tid & 63;
    const int tx = sp & 7;
    const int ty = sp >> 3;
    // wave-uniform o-group base -> weight loads become s_load feeding v_min v,s,v
    const int o0 = __builtin_amdgcn_readfirstlane((tid >> 6) * OG);

    float acc[OG];
    #pragma unroll
    for (int i = 0; i < OG; ++i) acc[i] = -INFINITY;

    const float* wbase = kern + (size_t)o0 * (C_IN * 9);
    const float* xsbase = &lds[ty * LROW + tx];

    #pragma unroll 4
    for (int c = 0; c < C_IN; ++c) {
        const float* xs = xsbase + c * LPLANE;
        float xv[9];
        #pragma unroll
        for (int kh = 0; kh < 3; ++kh)
            #pragma unroll
            for (int kw = 0; kw < 3; ++kw)
                xv[kh * 3 + kw] = xs[kh * LROW + kw];   // ds_read, imm offsets

        const float* wp8 = wbase + c * 9;
        #pragma unroll
        for (int oo = 0; oo < OG; ++oo) {
            const float* wp = wp8 + (size_t)oo * (C_IN * 9);   // uniform -> s_load
            float m0 = fminf(xv[0], wp[0]);
            float m1 = fminf(xv[1], wp[1]);
            float m2 = fminf(xv[2], wp[2]);
            float m3 = fminf(xv[3], wp[3]);
            float m4 = fminf(xv[4], wp[4]);
            float m5 = fminf(xv[5], wp[5]);
            float m6 = fminf(xv[6], wp[6]);
            float m7 = fminf(xv[7], wp[7]);
            float m8 = fminf(xv[8], wp[8]);
            // fmaxf(fmaxf(a,b),c) -> v_max3_f32
            float r0 = fmaxf(fmaxf(m0, m1), m2);
            float r1 = fmaxf(fmaxf(m3, m4), m5);
            float r2 = fmaxf(fmaxf(m6, m7), m8);
            acc[oo] = fmaxf(acc[oo], fmaxf(fmaxf(r0, r1), r2));
        }
    }

    float* op = out + (((size_t)n * O_OUT + o0) * HIMG + (ti0 + ty)) * WIMG
                    + (tj0 + tx);
    #pragma unroll
    for (int oo = 0; oo < OG; ++oo)
        op[(size_t)oo * (HIMG * WIMG)] = acc[oo];
}

extern "C" void kernel_launch(void* const* d_in, const int* in_sizes, int n_in,
                              void* d_out, int out_size, void* d_ws, size_t ws_size,
                              hipStream_t stream) {
    const float* x    = (const float*)d_in[0];
    const float* kern = (const float*)d_in[1];
    float* out        = (float*)d_out;
    dim3 grid(WIMG / TS, HIMG / TS, 8);   // (14, 14, 8)
    dim3 block(256);
    semiconv_kernel<<<grid, block, 0, stream>>>(x, kern, out);
}

// Round 4
// 98.541 us; speedup vs baseline: 1.0112x; 1.0112x over previous
//
#include <hip/hip_runtime.h>
#include <math.h>

#define C_IN  32
#define O_OUT 32
#define HIMG  112
#define WIMG  112
#define TI    8      // output rows per block
#define TJ    16     // output cols per block
#define OG    8      // output channels per block
#define CW    8      // input channels per wave (4 waves x 8 = 32)
#define XROW  20     // padded halo row stride (18 used)
#define XPLANE (10 * XROW)   // 200 floats per channel plane
#define WPAD  12     // weights padded 9->12 so (oo,c) slab is 16B-aligned

// Tropical (max-min) 3x3 conv, 'same' padding with -inf.
// out[n,o,i,j] = max_{c,kh,kw} min(x[n,c,i+kh-1,j+kw-1], w[o,c,kh,kw])
// Block: 8x16 spatial tile, 8 o's; 4 waves split c (8 each); LDS max-combine.
// Weights live in LDS (ds_read broadcast) -- NO s_load in the hot loop, so
// lgkmcnt is homogeneous/in-order and the scalar cache can't thrash.
__global__ __launch_bounds__(256, 4) void semiconv_kernel(
    const float* __restrict__ x, const float* __restrict__ kern,
    float* __restrict__ out)
{
    __shared__ float xs[C_IN * XPLANE];        // 25600 B
    __shared__ float ws[OG * C_IN * WPAD];     // 12288 B  (total 37.9 KB -> 4 blk/CU)

    const int tid = threadIdx.x;
    const int tj0 = blockIdx.x * TJ;
    const int ti0 = blockIdx.y * TI;
    const int n   = blockIdx.z >> 2;
    const int o0  = (blockIdx.z & 3) * OG;

    const float* xn = x + (size_t)n * (C_IN * HIMG * WIMG);

    // ---- stage x halo: rows ti0-1..ti0+8, cols tj0-1..tj0+16 -> [10][20] padded
    #pragma unroll 1
    for (int idx = tid; idx < C_IN * XPLANE; idx += 256) {
        int c   = idx / XPLANE;
        int rem = idx - c * XPLANE;
        int r   = rem / XROW;
        int col = rem - r * XROW;
        int gi = ti0 - 1 + r;
        int gj = tj0 - 1 + col;
        float v = -INFINITY;
        if (col < 18 && (unsigned)gi < (unsigned)HIMG && (unsigned)gj < (unsigned)WIMG)
            v = xn[c * (HIMG * WIMG) + gi * WIMG + gj];
        xs[idx] = v;
    }
    // ---- stage weights: ws[(oo*32 + c)*12 + k] = kern[(o0+oo)*32*9 + c*9 + k]
    const float* wg = kern + (size_t)o0 * (C_IN * 9);
    #pragma unroll 1
    for (int idx = tid; idx < OG * C_IN * WPAD; idx += 256) {
        int p = idx / WPAD;
        int k = idx - p * WPAD;
        ws[idx] = (k < 9) ? wg[p * 9 + k] : -INFINITY;
    }
    __syncthreads();

    const int lane = tid & 63;
    const int wv   = tid >> 6;          // wave id 0..3 -> c chunk
    const int r    = lane >> 3;         // output row 0..7
    const int j0   = (lane & 7) * 2;    // output col base 0,2,..,14

    float acc[OG][2];
    #pragma unroll
    for (int a = 0; a < OG; ++a) { acc[a][0] = -INFINITY; acc[a][1] = -INFINITY; }

    const int c0 = wv * CW;
    #pragma unroll 2
    for (int cc = 0; cc < CW; ++cc) {
        const int c = c0 + cc;
        // taps: halo rows r..r+2, halo cols j0..j0+3 (2 outputs x 3 kw)
        const float* xp = &xs[c * XPLANE + r * XROW + j0];
        float xv[3][4];
        #pragma unroll
        for (int kh = 0; kh < 3; ++kh) {
            float2 a2 = *(const float2*)(xp + kh * XROW);       // 8B aligned
            float2 b2 = *(const float2*)(xp + kh * XROW + 2);
            xv[kh][0] = a2.x; xv[kh][1] = a2.y; xv[kh][2] = b2.x; xv[kh][3] = b2.y;
        }
        #pragma unroll
        for (int oo = 0; oo < OG; ++oo) {
            const float* wp = &ws[(oo * C_IN + c) * WPAD];      // 48B-aligned
            float4 wa = *(const float4*)wp;                     // broadcast reads
            float4 wb = *(const float4*)(wp + 4);
            float  w8 = wp[8];
            #pragma unroll
            for (int q = 0; q < 2; ++q) {
                float t0 = fminf(xv[0][q + 0], wa.x);
                float t1 = fminf(xv[0][q + 1], wa.y);
                float t2 = fminf(xv[0][q + 2], wa.z);
                float t3 = fminf(xv[1][q + 0], wa.w);
                float t4 = fminf(xv[1][q + 1], wb.x);
                float t5 = fminf(xv[1][q + 2], wb.y);
                float t6 = fminf(xv[2][q + 0], wb.z);
                float t7 = fminf(xv[2][q + 1], wb.w);
                float t8 = fminf(xv[2][q + 2], w8);
                float r0 = fmaxf(fmaxf(t0, t1), t2);   // v_max3_f32
                float r1 = fmaxf(fmaxf(t3, t4), t5);
                float r2 = fmaxf(fmaxf(t6, t7), t8);
                acc[oo][q] = fmaxf(acc[oo][q], fmaxf(fmaxf(r0, r1), r2));
            }
        }
    }

    // ---- cross-wave max combine (partials over c-chunks), reusing xs
    __syncthreads();   // everyone done reading xs/ws
    #pragma unroll
    for (int oo = 0; oo < OG; ++oo) {
        float2 v; v.x = acc[oo][0]; v.y = acc[oo][1];
        *(float2*)&xs[wv * 1024 + oo * 128 + r * 16 + j0] = v;   // 8B aligned
    }
    __syncthreads();
    #pragma unroll
    for (int s = 0; s < 4; ++s) {
        int item = s * 256 + tid;                  // 0..1023 = oo*128 + px
        float v = fmaxf(fmaxf(xs[item], xs[1024 + item]),
                        fmaxf(xs[2048 + item], xs[3072 + item]));
        int oo = item >> 7;
        int px = item & 127;
        int rr = px >> 4;
        int jj = px & 15;
        out[(((size_t)(n * O_OUT + o0 + oo)) * HIMG + (ti0 + rr)) * WIMG
            + (tj0 + jj)] = v;
    }
}

extern "C" void kernel_launch(void* const* d_in, const int* in_sizes, int n_in,
                              void* d_out, int out_size, void* d_ws, size_t ws_size,
                              hipStream_t stream) {
    const float* x    = (const float*)d_in[0];
    const float* kern = (const float*)d_in[1];
    float* out        = (float*)d_out;
    dim3 grid(WIMG / TJ, HIMG / TI, 8 * 4);   // (7, 14, 32): n x o-group
    dim3 block(256);
    semiconv_kernel<<<grid, block, 0, stream>>>(x, kern, out);
}

// Round 6
// 73.091 us; speedup vs baseline: 1.3632x; 1.3482x over previous
//
#include <hip/hip_runtime.h>
#include <math.h>

#define C_IN  32
#define O_OUT 32
#define HIMG  112
#define WIMG  112
#define HW    (HIMG * WIMG)
#define TS    8            // spatial tile 8x8, one wave covers it
#define NCP   16           // c-pairs (channels packed 2-per-reg)
#define XROW  12           // packed-pairs per halo row (10 used; 12 -> exact 2-way banks, free)
#define XPLANE (10 * XROW) // 120 pairs per c-pair plane
#define WSLOT 16           // pairs per (o,cp) slot -> 64B aligned

typedef _Float16 h2 __attribute__((ext_vector_type(2)));

static __device__ __forceinline__ h2 h2min(h2 a, h2 b) {
#if __has_builtin(__builtin_elementwise_min)
    return __builtin_elementwise_min(a, b);
#else
    h2 r; asm("v_pk_min_f16 %0, %1, %2" : "=v"(r) : "v"(a), "v"(b)); return r;
#endif
}
static __device__ __forceinline__ h2 h2max(h2 a, h2 b) {
#if __has_builtin(__builtin_elementwise_max)
    return __builtin_elementwise_max(a, b);
#else
    h2 r; asm("v_pk_max_f16 %0, %1, %2" : "=v"(r) : "v"(a), "v"(b)); return r;
#endif
}

// Pack weights: wp[((o*NCP)+cp)*WSLOT + k] = (w[o,2cp,k], w[o,2cp+1,k]) as f16x2
__global__ void prep_weights(const float* __restrict__ kern, h2* __restrict__ wp)
{
    int idx = blockIdx.x * 256 + threadIdx.x;     // 32*16*16 = 8192 total
    if (idx >= O_OUT * NCP * WSLOT) return;
    int k  = idx & (WSLOT - 1);
    int cp = (idx >> 4) & (NCP - 1);
    int o  = idx >> 8;
    float a = -INFINITY, b = -INFINITY;
    if (k < 9) {
        a = kern[(o * C_IN + 2 * cp    ) * 9 + k];
        b = kern[(o * C_IN + 2 * cp + 1) * 9 + k];
    }
    h2 v; v.x = (_Float16)a; v.y = (_Float16)b;
    wp[idx] = v;
}

// Tropical (max-min) 3x3 conv in packed f16: abs err <= ~4e-3 << 7.6e-2 threshold.
// Wave = 8x8 tile x 8 o's; block = 4 waves = all 32 o; c-pairs packed in f16x2.
__global__ __launch_bounds__(256, 6) void semiconv_kernel(
    const float* __restrict__ x, const h2* __restrict__ wp,
    float* __restrict__ out)
{
    __shared__ h2 xs[NCP * XPLANE];   // 7680 B

    const int tid = threadIdx.x;
    const int tj0 = blockIdx.x * TS;
    const int ti0 = blockIdx.y * TS;
    const int n   = blockIdx.z;
    const float* xn = x + (size_t)n * (C_IN * HW);

    // Stage halo tile, channel-pair interleaved: xs[cp][r][col] = (x[2cp], x[2cp+1])
    #pragma unroll 1
    for (int idx = tid; idx < NCP * XPLANE; idx += 256) {
        int cp  = idx / XPLANE;
        int rem = idx - cp * XPLANE;
        int r   = rem / XROW;
        int col = rem - r * XROW;
        int gi = ti0 - 1 + r, gj = tj0 - 1 + col;
        float a = -INFINITY, b = -INFINITY;
        if (col < 10 && (unsigned)gi < (unsigned)HIMG && (unsigned)gj < (unsigned)WIMG) {
            const float* p = xn + (size_t)(2 * cp) * HW + gi * WIMG + gj;
            a = p[0];
            b = p[HW];
        }
        h2 v; v.x = (_Float16)a; v.y = (_Float16)b;
        xs[idx] = v;
    }
    __syncthreads();

    const int lane = tid & 63;
    const int wv   = tid >> 6;
    const int o0   = __builtin_amdgcn_readfirstlane(wv * 8);   // uniform -> s_load weights
    const int ty   = lane >> 3, tx = lane & 7;

    h2 ninf2; ninf2.x = (_Float16)(-INFINITY); ninf2.y = (_Float16)(-INFINITY);
    h2 acc[8];
    #pragma unroll
    for (int i = 0; i < 8; ++i) acc[i] = ninf2;

    const h2* xbase = &xs[ty * XROW + tx];
    const h2* wb    = wp + (size_t)o0 * (NCP * WSLOT);

    #pragma unroll 2
    for (int cp = 0; cp < NCP; ++cp) {
        const h2* xp = xbase + cp * XPLANE;
        h2 xv[9];
        #pragma unroll
        for (int kh = 0; kh < 3; ++kh)
            #pragma unroll
            for (int kw = 0; kw < 3; ++kw)
                xv[kh * 3 + kw] = xp[kh * XROW + kw];   // ds_read_b32, imm offsets

        #pragma unroll
        for (int oo = 0; oo < 8; ++oo) {
            const h2* w9 = wb + (oo * NCP + cp) * WSLOT;   // uniform, 64B-aligned
            h2 t0 = h2min(xv[0], w9[0]);
            h2 t1 = h2min(xv[1], w9[1]);
            h2 t2 = h2min(xv[2], w9[2]);
            h2 t3 = h2min(xv[3], w9[3]);
            h2 t4 = h2min(xv[4], w9[4]);
            h2 t5 = h2min(xv[5], w9[5]);
            h2 t6 = h2min(xv[6], w9[6]);
            h2 t7 = h2min(xv[7], w9[7]);
            h2 t8 = h2min(xv[8], w9[8]);
            h2 r0 = h2max(h2max(t0, t1), t2);
            h2 r1 = h2max(h2max(t3, t4), t5);
            h2 r2 = h2max(h2max(t6, t7), t8);
            acc[oo] = h2max(acc[oo], h2max(h2max(r0, r1), r2));
        }
    }

    // Reduce the two packed channels, convert to f32, store.
    #pragma unroll
    for (int oo = 0; oo < 8; ++oo) {
        _Float16 m = acc[oo].x > acc[oo].y ? acc[oo].x : acc[oo].y;
        out[(((size_t)n * O_OUT + o0 + oo) * HIMG + (ti0 + ty)) * WIMG + (tj0 + tx)]
            = (float)m;
    }
}

extern "C" void kernel_launch(void* const* d_in, const int* in_sizes, int n_in,
                              void* d_out, int out_size, void* d_ws, size_t ws_size,
                              hipStream_t stream) {
    const float* x    = (const float*)d_in[0];
    const float* kern = (const float*)d_in[1];
    float* out        = (float*)d_out;
    h2* wp            = (h2*)d_ws;                 // 32 KB of scratch

    prep_weights<<<dim3(32), dim3(256), 0, stream>>>(kern, wp);
    dim3 grid(WIMG / TS, HIMG / TS, 8);            // (14, 14, 8)
    semiconv_kernel<<<grid, dim3(256), 0, stream>>>(x, wp, out);
}

// Round 7
// 70.032 us; speedup vs baseline: 1.4228x; 1.0437x over previous
//
#include <hip/hip_runtime.h>
#include <math.h>

#define C_IN  32
#define O_OUT 32
#define HIMG  112
#define WIMG  112
#define HW    (HIMG * WIMG)
#define TS    8            // spatial tile 8x8, one wave covers it
#define NCP   16           // c-pairs (channels packed 2-per-reg)
#define XROW  10           // packed-pairs per halo row
#define XPLANE (10 * XROW) // 100 pairs per c-pair plane
#define WSLOT 12           // h2 per (cp,o) slot = 48 B -> b128-aligned
#define NW    (NCP * O_OUT * WSLOT)   // 6144 h2 = 24576 B

typedef _Float16 h2 __attribute__((ext_vector_type(2)));

static __device__ __forceinline__ h2 h2min(h2 a, h2 b) {
    return __builtin_elementwise_min(a, b);
}
static __device__ __forceinline__ h2 h2max(h2 a, h2 b) {
    return __builtin_elementwise_max(a, b);
}
static __device__ __forceinline__ h2 asH2(float f) {
    union { float f; h2 h; } u; u.f = f; return u.h;
}

// Pack weights: wp[(cp*32 + o)*WSLOT + k] = (w[o,2cp,k], w[o,2cp+1,k]) as f16x2
__global__ void prep_weights(const float* __restrict__ kern, h2* __restrict__ wp)
{
    int idx = blockIdx.x * 256 + threadIdx.x;     // 16*32*12 = 6144 total
    if (idx >= NW) return;
    int k  = idx % WSLOT;
    int o  = (idx / WSLOT) & 31;
    int cp = idx / (WSLOT * 32);
    float a = -INFINITY, b = -INFINITY;
    if (k < 9) {
        a = kern[(o * C_IN + 2 * cp    ) * 9 + k];
        b = kern[(o * C_IN + 2 * cp + 1) * 9 + k];
    }
    h2 v; v.x = (_Float16)a; v.y = (_Float16)b;
    wp[idx] = v;
}

// Tropical (max-min) 3x3 conv, packed f16 (abs err ~4e-3 << 7.6e-2 threshold).
// Wave = 8x8 tile x 8 o; block = 4 waves = all 32 o. Hot loop is DS-only:
// weights read from LDS via broadcast ds_read_b128 (in-order lgkmcnt ->
// compiler pipelines with partial waits; no SMEM drains, no K$ thrash).
__global__ __launch_bounds__(256, 4) void semiconv_kernel(
    const float* __restrict__ x, const h2* __restrict__ wp,
    float* __restrict__ out)
{
    __shared__ h2 xs[NCP * XPLANE];   // 6400 B
    __shared__ h2 ws[NW];             // 24576 B  (total 30976 -> 5 blocks/CU)

    const int tid = threadIdx.x;
    const int tj0 = blockIdx.x * TS;
    const int ti0 = blockIdx.y * TS;
    const int n   = blockIdx.z;
    const float* xn = x + (size_t)n * (C_IN * HW);

    // Stage packed weights (24.6 KB, L2-resident source): 6 x dwordx4 per thread.
    #pragma unroll
    for (int i = 0; i < NW / 1024; ++i) {          // 6 iterations
        int idx = i * 1024 + tid * 4;
        *(float4*)&ws[idx] = *(const float4*)&wp[idx];
    }
    // Stage x halo tile, channel-pair interleaved: xs[cp][r][col]
    #pragma unroll 1
    for (int idx = tid; idx < NCP * XPLANE; idx += 256) {
        int cp  = idx / XPLANE;
        int rem = idx - cp * XPLANE;
        int r   = rem / XROW;
        int col = rem - r * XROW;
        int gi = ti0 - 1 + r, gj = tj0 - 1 + col;
        float a = -INFINITY, b = -INFINITY;
        if ((unsigned)gi < (unsigned)HIMG && (unsigned)gj < (unsigned)WIMG) {
            const float* p = xn + (size_t)(2 * cp) * HW + gi * WIMG + gj;
            a = p[0];
            b = p[HW];
        }
        h2 v; v.x = (_Float16)a; v.y = (_Float16)b;
        xs[idx] = v;
    }
    __syncthreads();

    const int lane = tid & 63;
    const int wv   = tid >> 6;
    const int o0   = wv * 8;
    const int ty   = lane >> 3, tx = lane & 7;

    h2 ninf2; ninf2.x = (_Float16)(-INFINITY); ninf2.y = (_Float16)(-INFINITY);
    h2 acc[8];
    #pragma unroll
    for (int i = 0; i < 8; ++i) acc[i] = ninf2;

    const h2* xbase = &xs[ty * XROW + tx];

    #pragma unroll 2
    for (int cp = 0; cp < NCP; ++cp) {
        const h2* xp = xbase + cp * XPLANE;
        h2 xv[9];
        #pragma unroll
        for (int kh = 0; kh < 3; ++kh)
            #pragma unroll
            for (int kw = 0; kw < 3; ++kw)
                xv[kh * 3 + kw] = xp[kh * XROW + kw];   // ds_read_b32, imm offsets

        const h2* wrow = &ws[(cp * O_OUT + o0) * WSLOT]; // one VGPR base per cp
        #pragma unroll
        for (int oo = 0; oo < 8; ++oo) {
            // 48B slot: b128 (h2[0..3]) + b128 (h2[4..7]) + b32 (h2[8]),
            // same-address broadcast across lanes = conflict-free.
            const float4* w4 = (const float4*)(wrow + oo * WSLOT);
            float4 wa = w4[0];
            float4 wb = w4[1];
            float  wc = ((const float*)(wrow + oo * WSLOT))[8];
            h2 t0 = h2min(xv[0], asH2(wa.x));
            h2 t1 = h2min(xv[1], asH2(wa.y));
            h2 t2 = h2min(xv[2], asH2(wa.z));
            h2 t3 = h2min(xv[3], asH2(wa.w));
            h2 t4 = h2min(xv[4], asH2(wb.x));
            h2 t5 = h2min(xv[5], asH2(wb.y));
            h2 t6 = h2min(xv[6], asH2(wb.z));
            h2 t7 = h2min(xv[7], asH2(wb.w));
            h2 t8 = h2min(xv[8], asH2(wc));
            h2 r0 = h2max(h2max(t0, t1), t2);
            h2 r1 = h2max(h2max(t3, t4), t5);
            h2 r2 = h2max(h2max(t6, t7), t8);
            acc[oo] = h2max(acc[oo], h2max(h2max(r0, r1), r2));
        }
    }

    #pragma unroll
    for (int oo = 0; oo < 8; ++oo) {
        _Float16 m = acc[oo].x > acc[oo].y ? acc[oo].x : acc[oo].y;
        out[(((size_t)n * O_OUT + o0 + oo) * HIMG + (ti0 + ty)) * WIMG + (tj0 + tx)]
            = (float)m;
    }
}

extern "C" void kernel_launch(void* const* d_in, const int* in_sizes, int n_in,
                              void* d_out, int out_size, void* d_ws, size_t ws_size,
                              hipStream_t stream) {
    const float* x    = (const float*)d_in[0];
    const float* kern = (const float*)d_in[1];
    float* out        = (float*)d_out;
    h2* wp            = (h2*)d_ws;                 // 24.6 KB of scratch

    prep_weights<<<dim3((NW + 255) / 256), dim3(256), 0, stream>>>(kern, wp);
    dim3 grid(WIMG / TS, HIMG / TS, 8);            // (14, 14, 8)
    semiconv_kernel<<<grid, dim3(256), 0, stream>>>(x, wp, out);
}

// Round 8
// 59.590 us; speedup vs baseline: 1.6721x; 1.1752x over previous
//
#include <hip/hip_runtime.h>
#include <math.h>

#define C_IN  32
#define O_OUT 32
#define HIMG  112
#define WIMG  112
#define HW    (HIMG * WIMG)
#define TS    8            // spatial tile 8x8
#define NCP   16           // c-pairs (2 channels per f16x2 reg)
#define XROW  12           // h2 per halo row (10 used; 48B -> every row 16B-aligned)
#define XPLANE (10 * XROW) // 120 h2 per c-pair plane
#define WSLOT 12           // h2 per (o,cp) slot (9 used) -> 48B, b128-aligned
#define OSTRIDE 196        // h2 per o in LDS (16*12=192 used +4 pad -> distinct banks)
#define NW    (O_OUT * NCP * WSLOT)   // 6144 h2 = 24576 B in global scratch

typedef _Float16 h2 __attribute__((ext_vector_type(2)));

static __device__ __forceinline__ h2 h2min(h2 a, h2 b) {
    return __builtin_elementwise_min(a, b);
}
static __device__ __forceinline__ h2 h2max(h2 a, h2 b) {
    return __builtin_elementwise_max(a, b);
}
static __device__ __forceinline__ h2 asH2(float f) {
    union { float f; h2 h; } u; u.f = f; return u.h;
}

// Pack weights: wp[(o*NCP + cp)*WSLOT + k] = (w[o,2cp,k], w[o,2cp+1,k]) as f16x2
__global__ void prep_weights(const float* __restrict__ kern, h2* __restrict__ wp)
{
    int idx = blockIdx.x * 256 + threadIdx.x;     // 32*16*12 = 6144 total
    if (idx >= NW) return;
    int k  = idx % WSLOT;
    int cp = (idx / WSLOT) & (NCP - 1);
    int o  = idx / (WSLOT * NCP);
    float a = -INFINITY, b = -INFINITY;
    if (k < 9) {
        a = kern[(o * C_IN + 2 * cp    ) * 9 + k];
        b = kern[(o * C_IN + 2 * cp + 1) * 9 + k];
    }
    h2 v; v.x = (_Float16)a; v.y = (_Float16)b;
    wp[idx] = v;
}

// Tropical (max-min) 3x3 conv, packed f16 (abs err ~1.6e-2 << 7.6e-2 threshold).
// Lane = (o, px-row): each lane computes an 8-px output row for ONE o.
// Per cp-iter: 9 wide x-reads (rows shared across o-lanes, sliding-window reg
// reuse) + 3 weight reads -> 12 LDS instrs vs 33 in the px-lane layout.
__global__ __launch_bounds__(256, 4) void semiconv_kernel(
    const float* __restrict__ x, const h2* __restrict__ wp,
    float* __restrict__ out)
{
    __shared__ h2 xs[NCP * XPLANE];     // 7680 B
    __shared__ h2 ws[O_OUT * OSTRIDE];  // 25088 B  (total 32768 -> 5 blocks/CU)

    const int tid = threadIdx.x;
    const int tj0 = blockIdx.x * TS;
    const int ti0 = blockIdx.y * TS;
    const int n   = blockIdx.z;
    const float* xn = x + (size_t)n * (C_IN * HW);

    // ---- stage packed weights global->LDS with o-stride pad 192->196 dwords
    #pragma unroll
    for (int i = 0; i < 6; ++i) {                  // 1536 16B-chunks total
        int chunk = i * 256 + tid;
        int o     = chunk / 48;                    // 48 chunks per o
        int rem   = chunk - o * 48;
        float4 v  = *(const float4*)&wp[chunk * 4];
        *(float4*)&ws[o * OSTRIDE + rem * 4] = v;  // o*784B is 16B-aligned
    }
    // ---- stage x halo tile, channel-pair interleaved: xs[cp][r][col]
    #pragma unroll 1
    for (int idx = tid; idx < NCP * XPLANE; idx += 256) {
        int cp  = idx / XPLANE;
        int rem = idx - cp * XPLANE;
        int r   = rem / XROW;
        int col = rem - r * XROW;
        int gi = ti0 - 1 + r, gj = tj0 - 1 + col;
        float a = -INFINITY, b = -INFINITY;
        if (col < 10 && (unsigned)gi < (unsigned)HIMG && (unsigned)gj < (unsigned)WIMG) {
            const float* p = xn + (size_t)(2 * cp) * HW + gi * WIMG + gj;
            a = p[0];
            b = p[HW];
        }
        h2 v; v.x = (_Float16)a; v.y = (_Float16)b;
        xs[idx] = v;
    }
    __syncthreads();

    const int lane = tid & 63;
    const int wv   = tid >> 6;
    const int oL   = lane >> 3;              // o within wave's slab, 0..7
    const int pr   = lane & 7;               // output px-row, 0..7
    const int o    = wv * 8 + oL;            // global o, 0..31

    h2 ninf2; ninf2.x = (_Float16)(-INFINITY); ninf2.y = (_Float16)(-INFINITY);
    h2 acc[8];
    #pragma unroll
    for (int i = 0; i < 8; ++i) acc[i] = ninf2;

    #pragma unroll 2
    for (int cp = 0; cp < NCP; ++cp) {
        // x: 3 halo rows x 10 cols, wide reads (broadcast across the 8 o-lanes
        // sharing pr; banks 12*pr mod 32 all distinct across pr)
        h2 xr[3][10];
        #pragma unroll
        for (int kh = 0; kh < 3; ++kh) {
            const h2* rp = &xs[cp * XPLANE + (pr + kh) * XROW];
            float4 a = *(const float4*)rp;         // cols 0-3
            float4 b = *(const float4*)(rp + 4);   // cols 4-7
            float2 c = *(const float2*)(rp + 8);   // cols 8-9
            xr[kh][0] = asH2(a.x); xr[kh][1] = asH2(a.y);
            xr[kh][2] = asH2(a.z); xr[kh][3] = asH2(a.w);
            xr[kh][4] = asH2(b.x); xr[kh][5] = asH2(b.y);
            xr[kh][6] = asH2(b.z); xr[kh][7] = asH2(b.w);
            xr[kh][8] = asH2(c.x); xr[kh][9] = asH2(c.y);
        }
        // w: my o's 9 taps (broadcast within o-group; banks 4*oL distinct)
        const h2* wq = &ws[o * OSTRIDE + cp * WSLOT];
        float4 wa = *(const float4*)wq;
        float4 wb = *(const float4*)(wq + 4);
        float  wc = *(const float*)(wq + 8);
        h2 w0 = asH2(wa.x), w1 = asH2(wa.y), w2 = asH2(wa.z), w3 = asH2(wa.w);
        h2 w4 = asH2(wb.x), w5 = asH2(wb.y), w6 = asH2(wb.z), w7 = asH2(wb.w);
        h2 w8 = asH2(wc);

        #pragma unroll
        for (int j = 0; j < 8; ++j) {
            h2 t0 = h2min(xr[0][j    ], w0);
            h2 t1 = h2min(xr[0][j + 1], w1);
            h2 t2 = h2min(xr[0][j + 2], w2);
            h2 t3 = h2min(xr[1][j    ], w3);
            h2 t4 = h2min(xr[1][j + 1], w4);
            h2 t5 = h2min(xr[1][j + 2], w5);
            h2 t6 = h2min(xr[2][j    ], w6);
            h2 t7 = h2min(xr[2][j + 1], w7);
            h2 t8 = h2min(xr[2][j + 2], w8);
            h2 r0 = h2max(h2max(t0, t1), t2);
            h2 r1 = h2max(h2max(t3, t4), t5);
            h2 r2 = h2max(h2max(t6, t7), t8);
            acc[j] = h2max(acc[j], h2max(h2max(r0, r1), r2));
        }
    }

    // Each lane owns a full output row: 8 consecutive f32 -> 2x dwordx4.
    float* op = out + (((size_t)n * O_OUT + o) * HIMG + (ti0 + pr)) * WIMG + tj0;
    float4 v0, v1;
    v0.x = (float)(acc[0].x > acc[0].y ? acc[0].x : acc[0].y);
    v0.y = (float)(acc[1].x > acc[1].y ? acc[1].x : acc[1].y);
    v0.z = (float)(acc[2].x > acc[2].y ? acc[2].x : acc[2].y);
    v0.w = (float)(acc[3].x > acc[3].y ? acc[3].x : acc[3].y);
    v1.x = (float)(acc[4].x > acc[4].y ? acc[4].x : acc[4].y);
    v1.y = (float)(acc[5].x > acc[5].y ? acc[5].x : acc[5].y);
    v1.z = (float)(acc[6].x > acc[6].y ? acc[6].x : acc[6].y);
    v1.w = (float)(acc[7].x > acc[7].y ? acc[7].x : acc[7].y);
    *(float4*)op = v0;
    *(float4*)(op + 4) = v1;
}

extern "C" void kernel_launch(void* const* d_in, const int* in_sizes, int n_in,
                              void* d_out, int out_size, void* d_ws, size_t ws_size,
                              hipStream_t stream) {
    const float* x    = (const float*)d_in[0];
    const float* kern = (const float*)d_in[1];
    float* out        = (float*)d_out;
    h2* wp            = (h2*)d_ws;                 // 24.6 KB of scratch

    prep_weights<<<dim3((NW + 255) / 256), dim3(256), 0, stream>>>(kern, wp);
    dim3 grid(WIMG / TS, HIMG / TS, 8);            // (14, 14, 8)
    semiconv_kernel<<<grid, dim3(256), 0, stream>>>(x, wp, out);
}